// Round 1
// baseline (6358.982 us; speedup 1.0000x reference)
//
#include <hip/hip_runtime.h>

#define T_DIM 256
#define B_DIM 128
#define F_DIM 1024
#define G_DIM 4096
#define NWG   64

typedef short bf8  __attribute__((ext_vector_type(8)));
typedef float f32x4 __attribute__((ext_vector_type(4)));

// ---- ws layout (bytes) ----
#define OFF_CTRL  0ull
#define OFF_WI    1024ull
#define SZ_WPACK  (8ull*1024*1024)     // 256nt * 32kt * 64lane * 8 elems * 2B
#define OFF_WH    (OFF_WI + SZ_WPACK)
#define OFF_X     (OFF_WH + SZ_WPACK)
#define SZ_XPACK  (64ull*1024*1024)    // 256t * 131072 elems * 2B
#define OFF_H     (OFF_X + SZ_XPACK)   // 2 buffers * 131072 elems * 2B
#define WS_NEED   (OFF_H + 2ull*131072ull*2ull)

__device__ __forceinline__ unsigned short f2bf(float v) {
  union { float f; unsigned int u; } c; c.f = v;
  unsigned int u = c.u;
  return (unsigned short)((u + 0x7fffu + ((u >> 16) & 1u)) >> 16);  // RNE
}
__device__ __forceinline__ float sigm(float x)  { return 1.f / (1.f + __expf(-x)); }
__device__ __forceinline__ float tanh_(float x) { return 1.f - 2.f / (1.f + __expf(2.f * x)); }

// ---- pack W (fp32 row-major F x 4F) -> MFMA-B fragment order, bf16 ----
// elem(k,col): nt=col>>4, kt=k>>5, lane=(col&15)|(((k>>3)&3)<<4), j=k&7
// flat = ((nt*32+kt)*64+lane)*8 + j
__global__ __launch_bounds__(256) void pack_w(const float* __restrict__ Wi,
                                              const float* __restrict__ Wh,
                                              unsigned short* __restrict__ wip,
                                              unsigned short* __restrict__ whp) {
  int gid = blockIdx.x * 256 + threadIdx.x;          // 0 .. 2*524288-1
  const float* src = (gid >= 524288) ? Wh : Wi;
  unsigned short* dst = (gid >= 524288) ? whp : wip;
  int r  = gid & 524287;
  int nt = r >> 11;
  int kt = (r >> 6) & 31;
  int l  = r & 63;
  int col = nt * 16 + (l & 15);
  int k0  = kt * 32 + ((l >> 4) << 3);
  bf8 v8;
#pragma unroll
  for (int j = 0; j < 8; ++j)
    v8[j] = (short)f2bf(src[(size_t)(k0 + j) * G_DIM + col]);
  *reinterpret_cast<bf8*>(dst + (size_t)r * 8) = v8;
}

// ---- pack x (fp32 (T,B,F)) -> per-t MFMA-A fragment order, bf16 ----
// per t: [kt(32)][mt(8)][lane(64)][8]; elem(b,f): kt=f>>5, mt=b>>4,
// lane=(b&15)|(((f>>3)&3)<<4), j=f&7
__global__ __launch_bounds__(256) void pack_x(const float* __restrict__ x,
                                              unsigned short* __restrict__ xp) {
  int gid = blockIdx.x * 256 + threadIdx.x;          // T*32*8*64 = 4,194,304
  int t  = gid >> 14;
  int r  = gid & 16383;
  int kt = r >> 9;
  int m  = (r >> 6) & 7;
  int l  = r & 63;
  int b  = m * 16 + (l & 15);
  int f0 = kt * 32 + ((l >> 4) << 3);
  const float* s = x + ((size_t)(t * B_DIM + b)) * F_DIM + f0;
  bf8 v8;
#pragma unroll
  for (int j = 0; j < 8; ++j) v8[j] = (short)f2bf(s[j]);
  *reinterpret_cast<bf8*>(xp + (size_t)gid * 8) = v8;
}

__global__ __launch_bounds__(256) void pack_h(const float* __restrict__ h0,
                                              unsigned short* __restrict__ hp) {
  int gid = blockIdx.x * 256 + threadIdx.x;          // 16384
  int kt = gid >> 9;
  int m  = (gid >> 6) & 7;
  int l  = gid & 63;
  int b  = m * 16 + (l & 15);
  int f0 = kt * 32 + ((l >> 4) << 3);
  const float* s = h0 + (size_t)b * F_DIM + f0;
  bf8 v8;
#pragma unroll
  for (int j = 0; j < 8; ++j) v8[j] = (short)f2bf(s[j]);
  *reinterpret_cast<bf8*>(hp + (size_t)gid * 8) = v8;
}

// ---- persistent scan kernel: 64 WGs x 1024 threads ----
// WG wg owns f-columns [wg*16, wg*16+16) => gate ntiles g*64+wg, g=0..3 (i,f,g,o)
// wave w: khalf=w>>3 (0: x@Wi, 1: h@Wh), mt=w&7 (rows 16mt..16mt+15)
__global__ __launch_bounds__(1024) void lstm_scan(
    const unsigned short* __restrict__ xp,
    const unsigned short* __restrict__ wip,
    const unsigned short* __restrict__ whp,
    unsigned short* __restrict__ hp,           // 2 x 131072 elems
    const float* __restrict__ bias,
    const int*   __restrict__ term,
    const float* __restrict__ c0,
    float* __restrict__ out,
    unsigned int* __restrict__ ctrl) {
  __shared__ float ldsp[8][4][16][17];         // x-partials [mt][g][row][col]

  const int wg    = blockIdx.x;
  const int tid   = threadIdx.x;
  const int wv    = tid >> 6;
  const int lane  = tid & 63;
  const int khalf = wv >> 3;
  const int mt    = wv & 7;
  const int fi    = wg * 16 + (lane & 15);
  const int bl0   = (lane >> 4) << 2;

  float c_reg[4]  = {0.f, 0.f, 0.f, 0.f};
  float bias_r[4] = {0.f, 0.f, 0.f, 0.f};
  if (khalf == 1) {
#pragma unroll
    for (int r = 0; r < 4; ++r)
      c_reg[r] = c0[(size_t)(mt * 16 + bl0 + r) * F_DIM + fi];
#pragma unroll
    for (int g = 0; g < 4; ++g)
      bias_r[g] = bias[g * F_DIM + fi];
  }

  const unsigned short* wsel = khalf ? whp : wip;
  const bf8* bp[4];
#pragma unroll
  for (int g = 0; g < 4; ++g)
    bp[g] = reinterpret_cast<const bf8*>(wsel + (size_t)(g * 64 + wg) * 16384 + lane * 8);

  float* fc = out + (size_t)T_DIM * B_DIM * F_DIM;
  float* fh = fc + (size_t)B_DIM * F_DIM;

  unsigned int p = 0;
  for (int t = 0; t < T_DIM; ++t) {
    f32x4 acc[4] = {{0,0,0,0},{0,0,0,0},{0,0,0,0},{0,0,0,0}};
    const unsigned short* abase =
        khalf ? (const unsigned short*)hp + (size_t)p * 131072
              : xp + (size_t)t * 131072;
    const bf8* ap = reinterpret_cast<const bf8*>(abase + mt * 512 + lane * 8);

#pragma unroll 4
    for (int kt = 0; kt < 32; ++kt) {
      bf8 a = ap[kt * 512];                    // kt stride = 4096 elems
#pragma unroll
      for (int g = 0; g < 4; ++g)
        acc[g] = __builtin_amdgcn_mfma_f32_16x16x32_bf16(a, bp[g][kt * 64], acc[g], 0, 0, 0);
    }

    if (khalf == 0) {
#pragma unroll
      for (int g = 0; g < 4; ++g)
#pragma unroll
        for (int r = 0; r < 4; ++r)
          ldsp[mt][g][bl0 + r][lane & 15] = acc[g][r];
    }
    __syncthreads();

    if (khalf == 1) {
#pragma unroll
      for (int r = 0; r < 4; ++r) {
        int bl = bl0 + r;
        int b  = mt * 16 + bl;
        int trm = term[t * B_DIM + b];
        float hx[4];
#pragma unroll
        for (int g = 0; g < 4; ++g)
          hx[g] = ldsp[mt][g][bl][lane & 15] + bias_r[g] + (trm ? 0.f : acc[g][r]);
        float cp = trm ? 0.f : c_reg[r];
        float cn = sigm(hx[1]) * cp + sigm(hx[0]) * tanh_(hx[2]);
        float hn = sigm(hx[3]) * tanh_(cn);
        c_reg[r] = cn;
        out[((size_t)t * B_DIM + b) * F_DIM + fi] = hn;
        // repack h for next step's A-fragments
        int kt2 = fi >> 5;
        int l2  = (b & 15) | (((fi >> 3) & 3) << 4);
        hp[(size_t)(p ^ 1) * 131072 + (size_t)((kt2 * 8 + mt) * 64 + l2) * 8 + (fi & 7)] = f2bf(hn);
        if (t == T_DIM - 1) {
          fc[(size_t)b * F_DIM + fi] = cn;
          fh[(size_t)b * F_DIM + fi] = hn;
        }
      }
    }
    __syncthreads();

    // grid barrier: release h writes, acquire everyone else's
    if (tid == 0) {
      __hip_atomic_fetch_add(ctrl, 1u, __ATOMIC_RELEASE, __HIP_MEMORY_SCOPE_AGENT);
      unsigned int tgt = (unsigned int)NWG * (unsigned int)(t + 1);
      while (__hip_atomic_load(ctrl, __ATOMIC_RELAXED, __HIP_MEMORY_SCOPE_AGENT) < tgt)
        __builtin_amdgcn_s_sleep(1);
      (void)__hip_atomic_load(ctrl, __ATOMIC_ACQUIRE, __HIP_MEMORY_SCOPE_AGENT);
    }
    __syncthreads();
    p ^= 1;
  }
}

extern "C" void kernel_launch(void* const* d_in, const int* in_sizes, int n_in,
                              void* d_out, int out_size, void* d_ws, size_t ws_size,
                              hipStream_t stream) {
  const float* x    = (const float*)d_in[0];
  const int*   term = (const int*)d_in[1];
  const float* c0   = (const float*)d_in[2];
  const float* h0   = (const float*)d_in[3];
  const float* Wi   = (const float*)d_in[4];
  const float* Wh   = (const float*)d_in[5];
  const float* bias = (const float*)d_in[6];
  float* out = (float*)d_out;
  char*  ws  = (char*)d_ws;

  if (ws_size < WS_NEED) return;  // insufficient scratch: bail (output stays poisoned)

  unsigned int*   ctrl = (unsigned int*)(ws + OFF_CTRL);
  unsigned short* wip  = (unsigned short*)(ws + OFF_WI);
  unsigned short* whp  = (unsigned short*)(ws + OFF_WH);
  unsigned short* xp   = (unsigned short*)(ws + OFF_X);
  unsigned short* hp   = (unsigned short*)(ws + OFF_H);

  hipMemsetAsync(ctrl, 0, 256, stream);
  pack_w<<<dim3(4096),  dim3(256), 0, stream>>>(Wi, Wh, wip, whp);
  pack_x<<<dim3(16384), dim3(256), 0, stream>>>(x, xp);
  pack_h<<<dim3(64),    dim3(256), 0, stream>>>(h0, hp);
  lstm_scan<<<dim3(NWG), dim3(1024), 0, stream>>>(xp, wip, whp, hp, bias, term, c0, out, ctrl);
}